// Round 8
// baseline (295.365 us; speedup 1.0000x reference)
//
#include <hip/hip_runtime.h>
#include <hip/hip_bf16.h>
#include <stdint.h>

typedef unsigned short u16_t;
typedef __attribute__((ext_vector_type(8))) short short8;
typedef __attribute__((ext_vector_type(4))) float f32x4;
typedef __attribute__((ext_vector_type(4))) unsigned short us4;

__device__ __forceinline__ float bf2f(u16_t u) {
  union { unsigned int i; float f; } c; c.i = ((unsigned int)u) << 16; return c.f;
}
__device__ __forceinline__ u16_t f2bf(float f) {
  union { float f; unsigned int i; } c; c.f = f;
  unsigned int x = c.i;
  unsigned int r = x + 0x7fffu + ((x >> 16) & 1u);
  return (u16_t)(r >> 16);
}

__device__ __forceinline__ void gload_lds16(const u16_t* g, u16_t* l) {
  __builtin_amdgcn_global_load_lds(
      (const __attribute__((address_space(1))) void*)g,
      (__attribute__((address_space(3))) void*)(unsigned int)(uintptr_t)l,
      16, 0, 0);
}

struct Seg {
  const u16_t* Ah;
  const u16_t* Al;
  const u16_t* Bh;
  const u16_t* Bl;
  int boff;
};

struct GemmArgs {
  Seg segs[9];
  int nseg;
  int segs_per_split;
  int K;
  int ldA, ldB;
  long long sA, sB;
  float alpha;
  float* outf;
  long long sOut;
  long long sSplit;
  int ldT;
};

// Fused-split TN GEMM.  MODE 0: Ah*Bh+Al*Bh+Ah*Bl; 1: Ah*Bh+Ah*Bl; 2: Ah*Bh.
// NCH = k-chunks (of 8) staged per barrier pair. fp32 transposed store.
template<int BM, int BN, int MODE, bool PADB, int NCH = 4>
__global__ __launch_bounds__(256, 4) void gemm_tn(GemmArgs args) {
  constexpr int FM = BM / 32, FN = BN / 32;
  constexpr int AH_E = NCH * BM * 8;
  constexpr int AL_E = (MODE == 0) ? NCH * BM * 8 : 8;
  constexpr int BH_E = NCH * BN * 8;
  constexpr int BL_E = (MODE <= 1) ? NCH * BN * 8 : 8;
  constexpr int SM_E = AH_E + AL_E + BH_E + BL_E;
  __shared__ __align__(16) u16_t smem[SM_E];
  u16_t* aflat_h = smem;
  u16_t* aflat_l = smem + AH_E;
  u16_t* bflat_h = smem + AH_E + AL_E;
  u16_t* bflat_l = smem + AH_E + AL_E + BH_E;

  const int tid = threadIdx.x;
  const int wave = tid >> 6, lane = tid & 63;
  const int lhi = lane >> 4, llo = lane & 15;
  const int wr = wave >> 1, wc = wave & 1;
  const int nt = blockIdx.x, mt = blockIdx.y;
  const int b = blockIdx.z & 1, split = blockIdx.z >> 1;
  const int row0 = mt * BM, col0 = nt * BN;

  f32x4 acc[FM][FN];
  const f32x4 zero4 = {0.f, 0.f, 0.f, 0.f};
#pragma unroll
  for (int i = 0; i < FM; ++i)
#pragma unroll
    for (int j = 0; j < FN; ++j) acc[i][j] = zero4;

  constexpr int RA = BM * NCH / 256;
  constexpr int RB = BN * NCH / 256;

  const int s0 = split * args.segs_per_split;
  int s1 = s0 + args.segs_per_split;
  if (s1 > args.nseg) s1 = args.nseg;

  for (int s = s0; s < s1; ++s) {
    const u16_t* Abh = args.segs[s].Ah + (size_t)b * args.sA;
    const u16_t* Abl = args.segs[s].Al + (size_t)b * args.sA;
    const u16_t* Bbh = args.segs[s].Bh + (size_t)b * args.sB;
    const u16_t* Bbl = args.segs[s].Bl + (size_t)b * args.sB;
    const int boff = args.segs[s].boff;
    for (int k0 = 0; k0 < args.K; k0 += NCH * 8) {
      __syncthreads();
#pragma unroll
      for (int r = 0; r < RA; ++r) {
        int idx = r * 256 + tid;
        int chunk = idx / BM, m = idx % BM;
        size_t goff = (size_t)(row0 + m) * args.ldA + (k0 + chunk * 8);
        gload_lds16(Abh + goff, aflat_h + (size_t)idx * 8);
        if (MODE == 0)
          gload_lds16(Abl + goff, aflat_l + (size_t)idx * 8);
      }
#pragma unroll
      for (int r = 0; r < RB; ++r) {
        int idx = r * 256 + tid;
        int chunk = idx / BN, n = idx % BN;
        long long rowi;
        if (PADB) {
          int gn = col0 + n;
          rowi = (long long)((gn >> 6) + 1) * 66 + (gn & 63) + 1 + boff;
        } else {
          rowi = col0 + n;
        }
        size_t goff = (size_t)rowi * args.ldB + (k0 + chunk * 8);
        gload_lds16(Bbh + goff, bflat_h + (size_t)idx * 8);
        if (MODE <= 1)
          gload_lds16(Bbl + goff, bflat_l + (size_t)idx * 8);
      }
      __syncthreads();
#pragma unroll
      for (int kk = 0; kk < NCH / 4; ++kk) {
        const int ckA = (kk * 4 + lhi) * BM;
        const int ckB = (kk * 4 + lhi) * BN;
        short8 afh[FM], afl[FM], bfh[FN], bfl[FN];
#pragma unroll
        for (int i = 0; i < FM; ++i) {
          afh[i] = *(const short8*)(aflat_h + ((size_t)ckA + wr * (BM / 2) + i * 16 + llo) * 8);
          if (MODE == 0)
            afl[i] = *(const short8*)(aflat_l + ((size_t)ckA + wr * (BM / 2) + i * 16 + llo) * 8);
        }
#pragma unroll
        for (int j = 0; j < FN; ++j) {
          bfh[j] = *(const short8*)(bflat_h + ((size_t)ckB + wc * (BN / 2) + j * 16 + llo) * 8);
          if (MODE <= 1)
            bfl[j] = *(const short8*)(bflat_l + ((size_t)ckB + wc * (BN / 2) + j * 16 + llo) * 8);
        }
#pragma unroll
        for (int i = 0; i < FM; ++i)
#pragma unroll
          for (int j = 0; j < FN; ++j) {
            f32x4 t = acc[i][j];
            if (MODE <= 1)
              t = __builtin_amdgcn_mfma_f32_16x16x32_bf16(afh[i], bfl[j], t, 0, 0, 0);
            if (MODE == 0)
              t = __builtin_amdgcn_mfma_f32_16x16x32_bf16(afl[i], bfh[j], t, 0, 0, 0);
            t = __builtin_amdgcn_mfma_f32_16x16x32_bf16(afh[i], bfh[j], t, 0, 0, 0);
            acc[i][j] = t;
          }
      }
    }
  }

  float* outp = args.outf + (size_t)split * args.sSplit + (size_t)b * args.sOut;
#pragma unroll
  for (int i = 0; i < FM; ++i) {
    int mb = row0 + wr * (BM / 2) + i * 16 + lhi * 4;
#pragma unroll
    for (int j = 0; j < FN; ++j) {
      int n = col0 + wc * (BN / 2) + j * 16 + llo;
      f32x4 vv = acc[i][j] * args.alpha;
      *(f32x4*)(outp + (size_t)n * args.ldT + mb) = vv;
    }
  }
}

// ---- Fused QK + softmax (two-pass, symmetric upper triangle, MODE1) ----
// S[p][q] stored as sim[p][q]; tile (mt<=nt): normal side rows p in nt-block
// (slot mt), mirror side rows p in mt-block (slot nt). 32 slots per row.
struct QkArgs {
  const u16_t* fh;   // [2][4096][256]
  const u16_t* fl;
  float* pmax;       // [32][8192]
  float* psum;       // [32][8192]
  const float* mx;   // [8192]
  const float* rs;   // [8192]
  float* sim;        // [2][4096][4096]
  u16_t* Pb;         // [2][4096][4096]
};

template<int EPI>   // 0 = stats, 1 = write
__global__ __launch_bounds__(256, 4) void qk_symm(QkArgs args) {
  __shared__ __align__(16) u16_t smem[3 * 4096];
  u16_t* aflat_h = smem;
  u16_t* bflat_h = smem + 4096;
  u16_t* bflat_l = smem + 8192;

  const int tid = threadIdx.x;
  const int wave = tid >> 6, lane = tid & 63;
  const int lhi = lane >> 4, llo = lane & 15;
  const int wr = wave >> 1, wc = wave & 1;
  const int b = blockIdx.z;
  int t = blockIdx.x, r = 0;
  while (t >= 32 - r) { t -= 32 - r; ++r; }
  const int mt = r, nt = r + t;
  const int row0 = mt * 128, col0 = nt * 128;

  const u16_t* Fh = args.fh + (size_t)b * 4096 * 256;
  const u16_t* Fl = args.fl + (size_t)b * 4096 * 256;

  f32x4 acc[4][4];
  const f32x4 zero4 = {0.f, 0.f, 0.f, 0.f};
#pragma unroll
  for (int i = 0; i < 4; ++i)
#pragma unroll
    for (int j = 0; j < 4; ++j) acc[i][j] = zero4;

  for (int k0 = 0; k0 < 256; k0 += 32) {
    __syncthreads();
#pragma unroll
    for (int rr = 0; rr < 2; ++rr) {
      int idx = rr * 256 + tid;
      int chunk = idx >> 7, m = idx & 127;
      gload_lds16(Fh + (size_t)(row0 + m) * 256 + k0 + chunk * 8, aflat_h + (size_t)idx * 8);
      gload_lds16(Fh + (size_t)(col0 + m) * 256 + k0 + chunk * 8, bflat_h + (size_t)idx * 8);
      gload_lds16(Fl + (size_t)(col0 + m) * 256 + k0 + chunk * 8, bflat_l + (size_t)idx * 8);
    }
    __syncthreads();
    short8 afh[4], bfh[4], bfl[4];
#pragma unroll
    for (int i = 0; i < 4; ++i)
      afh[i] = *(const short8*)(aflat_h + ((size_t)lhi * 128 + wr * 64 + i * 16 + llo) * 8);
#pragma unroll
    for (int j = 0; j < 4; ++j) {
      bfh[j] = *(const short8*)(bflat_h + ((size_t)lhi * 128 + wc * 64 + j * 16 + llo) * 8);
      bfl[j] = *(const short8*)(bflat_l + ((size_t)lhi * 128 + wc * 64 + j * 16 + llo) * 8);
    }
#pragma unroll
    for (int i = 0; i < 4; ++i)
#pragma unroll
      for (int j = 0; j < 4; ++j) {
        f32x4 tt = acc[i][j];
        tt = __builtin_amdgcn_mfma_f32_16x16x32_bf16(afh[i], bfl[j], tt, 0, 0, 0);
        tt = __builtin_amdgcn_mfma_f32_16x16x32_bf16(afh[i], bfh[j], tt, 0, 0, 0);
        acc[i][j] = tt;
      }
  }
  // scale logits
#pragma unroll
  for (int i = 0; i < 4; ++i)
#pragma unroll
    for (int j = 0; j < 4; ++j) acc[i][j] *= 0.0625f;

  if (EPI == 0) {
    __syncthreads();
    float* nmax_l = (float*)smem;        // [2][128] by wr
    float* nsum_l = nmax_l + 256;
    float* mmax_l = nsum_l + 256;        // [2][128] by wc
    float* msum_l = mmax_l + 256;
    // n-side: rows p = n (reduce over m: i,r2 then lhi lanes)
#pragma unroll
    for (int j = 0; j < 4; ++j) {
      float m_ = -3.4e38f;
#pragma unroll
      for (int i = 0; i < 4; ++i)
#pragma unroll
        for (int r2 = 0; r2 < 4; ++r2) m_ = fmaxf(m_, acc[i][j][r2]);
      m_ = fmaxf(m_, __shfl_xor(m_, 16));
      m_ = fmaxf(m_, __shfl_xor(m_, 32));
      float su = 0.f;
#pragma unroll
      for (int i = 0; i < 4; ++i)
#pragma unroll
        for (int r2 = 0; r2 < 4; ++r2) su += __expf(acc[i][j][r2] - m_);
      su += __shfl_xor(su, 16);
      su += __shfl_xor(su, 32);
      if (lhi == 0) {
        int nl = wc * 64 + j * 16 + llo;
        nmax_l[wr * 128 + nl] = m_;
        nsum_l[wr * 128 + nl] = su;
      }
    }
    // m-side: rows p = m (reduce over n: j then llo lanes); skip on diagonal
    if (mt != nt) {
#pragma unroll
      for (int i = 0; i < 4; ++i)
#pragma unroll
        for (int r2 = 0; r2 < 4; ++r2) {
          float m_ = fmaxf(fmaxf(acc[0][0][r2], 0.f) * 0.f - 3.4e38f, -3.4e38f);
          m_ = -3.4e38f;
#pragma unroll
          for (int j = 0; j < 4; ++j) m_ = fmaxf(m_, acc[i][j][r2]);
          m_ = fmaxf(m_, __shfl_xor(m_, 1));
          m_ = fmaxf(m_, __shfl_xor(m_, 2));
          m_ = fmaxf(m_, __shfl_xor(m_, 4));
          m_ = fmaxf(m_, __shfl_xor(m_, 8));
          float su = 0.f;
#pragma unroll
          for (int j = 0; j < 4; ++j) su += __expf(acc[i][j][r2] - m_);
          su += __shfl_xor(su, 1);
          su += __shfl_xor(su, 2);
          su += __shfl_xor(su, 4);
          su += __shfl_xor(su, 8);
          if (llo == 0) {
            int ml = wr * 64 + i * 16 + lhi * 4 + r2;
            mmax_l[wc * 128 + ml] = m_;
            msum_l[wc * 128 + ml] = su;
          }
        }
    }
    __syncthreads();
    if (tid < 128) {
      float a0 = nmax_l[tid], a1 = nmax_l[128 + tid];
      float g = fmaxf(a0, a1);
      float su = nsum_l[tid] * __expf(a0 - g) + nsum_l[128 + tid] * __expf(a1 - g);
      size_t o = (size_t)mt * 8192 + (size_t)b * 4096 + col0 + tid;
      args.pmax[o] = g;
      args.psum[o] = su;
    } else if (mt != nt) {
      int ml = tid - 128;
      float a0 = mmax_l[ml], a1 = mmax_l[128 + ml];
      float g = fmaxf(a0, a1);
      float su = msum_l[ml] * __expf(a0 - g) + msum_l[128 + ml] * __expf(a1 - g);
      size_t o = (size_t)nt * 8192 + (size_t)b * 4096 + row0 + ml;
      args.pmax[o] = g;
      args.psum[o] = su;
    }
  } else {
    const float* MX = args.mx + (size_t)b * 4096;
    const float* RS = args.rs + (size_t)b * 4096;
    float* simb = args.sim + (size_t)b * 4096 * 4096;
    u16_t* Pbb = args.Pb + (size_t)b * 4096 * 4096;
    // normal side: rows p = n, cols m (coalesced f32x4 over m)
#pragma unroll
    for (int i = 0; i < 4; ++i) {
      int mb = row0 + wr * 64 + i * 16 + lhi * 4;
#pragma unroll
      for (int j = 0; j < 4; ++j) {
        int n = col0 + wc * 64 + j * 16 + llo;
        float mxn = MX[n], rsn = RS[n];
        f32x4 o;
        us4 h;
#pragma unroll
        for (int r2 = 0; r2 < 4; ++r2) {
          float e = __expf(acc[i][j][r2] - mxn) * rsn;
          o[r2] = e;
          h[r2] = f2bf(e);
        }
        *(f32x4*)(simb + (size_t)n * 4096 + mb) = o;
        *(us4*)(Pbb + (size_t)n * 4096 + mb) = h;
      }
    }
    // mirror side: rows p = m, cols n, via LDS transpose for coalescing
    if (mt != nt) {
      float* tb = (float*)smem;  // 32x132
#pragma unroll
      for (int i = 0; i < 4; ++i) {
        __syncthreads();
#pragma unroll
        for (int r2 = 0; r2 < 4; ++r2) {
          int m = row0 + wr * 64 + i * 16 + lhi * 4 + r2;
          float mxm = MX[m], rsm = RS[m];
          int trow = wr * 16 + lhi * 4 + r2;
#pragma unroll
          for (int j = 0; j < 4; ++j) {
            int tcol = wc * 64 + j * 16 + llo;
            tb[trow * 132 + tcol] = __expf(acc[i][j][r2] - mxm) * rsm;
          }
        }
        __syncthreads();
#pragma unroll
        for (int it = 0; it < 4; ++it) {
          int idx = it * 256 + tid;
          int row = idx >> 5, c4 = idx & 31;
          int mg = row0 + (row >> 4) * 64 + i * 16 + (row & 15);
          f32x4 v4 = *(f32x4*)&tb[row * 132 + c4 * 4];
          *(f32x4*)(simb + (size_t)mg * 4096 + col0 + c4 * 4) = v4;
          us4 h;
#pragma unroll
          for (int c = 0; c < 4; ++c) h[c] = f2bf(v4[c]);
          *(us4*)(Pbb + (size_t)mg * 4096 + col0 + c4 * 4) = h;
        }
      }
    }
  }
}

__global__ __launch_bounds__(256) void stat_reduce(
    const float* __restrict__ pmax, const float* __restrict__ psum,
    float* __restrict__ mx, float* __restrict__ rs) {
  int row = blockIdx.x * 256 + threadIdx.x;  // 8192 rows
  float g = -3.4e38f;
#pragma unroll
  for (int c = 0; c < 32; ++c) g = fmaxf(g, pmax[(size_t)c * 8192 + row]);
  float su = 0.f;
#pragma unroll
  for (int c = 0; c < 32; ++c)
    su += psum[(size_t)c * 8192 + row] * __expf(pmax[(size_t)c * 8192 + row] - g);
  mx[row] = g;
  rs[row] = 1.0f / su;
}

// Conv3x3 as 3 ty-splits; the 3 tx taps share ONE staged B tile with halo.
struct Conv3Args {
  const u16_t* W;
  const u16_t* X;
  float* outf;
  long long sOut;
  long long sSplit;
};
__global__ __launch_bounds__(256, 4) void conv3_gemm(Conv3Args a) {
  __shared__ __align__(16) u16_t lA[3][4][128][8];
  __shared__ __align__(16) u16_t lB[4 * 144 * 8];
  const int tid = threadIdx.x;
  const int wave = tid >> 6, lane = tid & 63;
  const int lhi = lane >> 4, llo = lane & 15;
  const int wr = wave >> 1, wc = wave & 1;
  const int nt = blockIdx.x, mt = blockIdx.y;
  const int b = blockIdx.z & 1, ty = blockIdx.z >> 1;
  const int row0 = mt * 128;
  const int base = (2 * nt + ty) * 66;
  const u16_t* Xb = a.X + (size_t)b * 4356 * 512;
  const u16_t* Wt = a.W + (size_t)(ty * 3) * 131072;

  f32x4 acc[4][4];
  const f32x4 zero4 = {0.f, 0.f, 0.f, 0.f};
#pragma unroll
  for (int i = 0; i < 4; ++i)
#pragma unroll
    for (int j = 0; j < 4; ++j) acc[i][j] = zero4;

  for (int k0 = 0; k0 < 512; k0 += 32) {
    __syncthreads();
#pragma unroll
    for (int t = 0; t < 3; ++t)
#pragma unroll
      for (int r = 0; r < 2; ++r) {
        int slot = r * 256 + tid;
        int chunk = slot >> 7, m = slot & 127;
        const u16_t* src = Wt + (size_t)t * 131072 + (size_t)(row0 + m) * 512 + k0 + chunk * 8;
        gload_lds16(src, &lA[t][0][0][0] + (size_t)slot * 8);
      }
#pragma unroll
    for (int r = 0; r < 2; ++r) {
      int idx = r * 256 + tid;
      int chunk = idx / 144, rr = idx % 144;
      gload_lds16(Xb + (size_t)(base + rr) * 512 + k0 + chunk * 8, lB + (size_t)idx * 8);
    }
    if (tid < 64) {
      int idx = 512 + tid;
      int chunk = idx / 144, rr = idx % 144;
      gload_lds16(Xb + (size_t)(base + rr) * 512 + k0 + chunk * 8, lB + (size_t)idx * 8);
    }
    __syncthreads();
#pragma unroll
    for (int t = 0; t < 3; ++t) {
      short8 af[4], bf[4];
#pragma unroll
      for (int i = 0; i < 4; ++i)
        af[i] = *(const short8*)&lA[t][lhi][wr * 64 + i * 16 + llo][0];
#pragma unroll
      for (int j = 0; j < 4; ++j) {
        int rB = wc * 66 + j * 16 + llo + t;
        bf[j] = *(const short8*)(lB + ((size_t)lhi * 144 + rB) * 8);
      }
#pragma unroll
      for (int i = 0; i < 4; ++i)
#pragma unroll
        for (int j = 0; j < 4; ++j)
          acc[i][j] = __builtin_amdgcn_mfma_f32_16x16x32_bf16(af[i], bf[j], acc[i][j], 0, 0, 0);
    }
  }

  float* outp = a.outf + (size_t)ty * a.sSplit + (size_t)b * a.sOut;
#pragma unroll
  for (int i = 0; i < 4; ++i) {
    int mb = row0 + wr * 64 + i * 16 + lhi * 4;
#pragma unroll
    for (int j = 0; j < 4; ++j) {
      int n = (nt << 7) + wc * 64 + j * 16 + llo;
      *(f32x4*)(outp + (size_t)n * 256 + mb) = acc[i][j];
    }
  }
}

template<int LDT, bool PER_COL>
__global__ __launch_bounds__(256) void reduce_split(
    const float* __restrict__ part, long long sSplit, int ns,
    const float* __restrict__ scale, const float* __restrict__ bias,
    u16_t* __restrict__ oh, u16_t* __restrict__ ol, long long total) {
  long long i = ((long long)blockIdx.x * 256 + threadIdx.x) * 4;
  if (i >= total) return;
  f32x4 s = *(const f32x4*)(part + i);
  for (int p = 1; p < ns; ++p) s += *(const f32x4*)(part + (size_t)p * sSplit + i);
  f32x4 v;
  if (PER_COL) {
    int c = (int)(i & (LDT - 1));
    f32x4 bi = *(const f32x4*)(bias + c);
    if (scale) { f32x4 sc = *(const f32x4*)(scale + c); v = s * sc + bi; }
    else v = s + bi;
  } else {
    int r = (int)((i / LDT) & 255);
    float bi = bias[r];
    v = s + bi;
  }
  us4 h, l;
#pragma unroll
  for (int c2 = 0; c2 < 4; ++c2) {
    float vv = v[c2] > 0.f ? v[c2] : 0.f;
    u16_t hh = f2bf(vv);
    h[c2] = hh;
    l[c2] = f2bf(vv - bf2f(hh));
  }
  *(us4*)(oh + i) = h;
  if (ol) *(us4*)(ol + i) = l;
}

__global__ __launch_bounds__(256) void reduce_split_f32(
    const float* __restrict__ part, long long sSplit, int ns,
    float* __restrict__ out, long long total) {
  long long i = ((long long)blockIdx.x * 256 + threadIdx.x) * 4;
  if (i >= total) return;
  f32x4 s = *(const f32x4*)(part + i);
  for (int p = 1; p < ns; ++p) s += *(const f32x4*)(part + (size_t)p * sSplit + i);
  *(f32x4*)(out + i) = s;
}

// x [2][512][4096] -> padded transposed split xT [2][4356][512] (hi/lo bf16).
__global__ __launch_bounds__(256) void xprep(const float* __restrict__ x,
                                             u16_t* __restrict__ xh, u16_t* __restrict__ xl) {
  __shared__ float tile[64][65];
  const int b = blockIdx.z, c0 = blockIdx.y * 64, n0 = blockIdx.x * 64;
  const float* xb = x + ((size_t)b * 512 + c0) * 4096 + n0;
  const int t = threadIdx.x;
  const int tr = t >> 6, tc = t & 63;
#pragma unroll
  for (int rr = 0; rr < 16; ++rr) {
    int ci = tr + rr * 4;
    tile[ci][tc] = xb[(size_t)ci * 4096 + tc];
  }
  __syncthreads();
#pragma unroll
  for (int rr = 0; rr < 16; ++rr) {
    int nj = rr * 4 + tr;
    float v = tile[tc][nj];
    size_t rp = (size_t)(blockIdx.x + 1) * 66 + nj + 1;
    size_t o = ((size_t)b * 4356 + rp) * 512 + c0 + tc;
    u16_t hh = f2bf(v);
    xh[o] = hh;
    xl[o] = f2bf(v - bf2f(hh));
  }
}

// Fused prep: bn | wk split | wv2 split | wv1 remap | zeropad
__global__ __launch_bounds__(256) void prep_all(
    const float* __restrict__ wk, const float* __restrict__ wv2, const float* __restrict__ wv1,
    const float* __restrict__ g, const float* __restrict__ be, const float* __restrict__ mu,
    const float* __restrict__ var, const float* __restrict__ bkb,
    u16_t* __restrict__ wkh, u16_t* __restrict__ wkl,
    u16_t* __restrict__ w2h, u16_t* __restrict__ w2l,
    u16_t* __restrict__ w1h, float* __restrict__ bnA, float* __restrict__ bnB,
    u16_t* __restrict__ xh, u16_t* __restrict__ xl) {
  long long i = (long long)blockIdx.x * 256 + threadIdx.x;
  if (i < 256) {
    float s = g[i] * rsqrtf(var[i] + 1e-5f);
    bnA[i] = s;
    bnB[i] = (bkb[i] - mu[i]) * s + be[i];
    return;
  }
  i -= 256;
  if (i < 131072) {
    float v = wk[i];
    u16_t hh = f2bf(v);
    wkh[i] = hh; wkl[i] = f2bf(v - bf2f(hh));
    return;
  }
  i -= 131072;
  if (i < 65536) {
    float v = wv2[i];
    u16_t hh = f2bf(v);
    w2h[i] = hh; w2l[i] = f2bf(v - bf2f(hh));
    return;
  }
  i -= 65536;
  if (i < 1179648) {
    int tp = (int)(i / (256 * 512));
    int rem = (int)(i % (256 * 512));
    int o = rem / 512, c = rem % 512;
    w1h[i] = f2bf(wv1[((size_t)o * 512 + c) * 9 + tp]);
    return;
  }
  i -= 1179648;
  if (i < 133120) {
    int blk = (int)(i >> 8), t = (int)(i & 255);
    int rowi = blk % 260, b = blk / 260;
    int rp;
    if (rowi < 66) rp = rowi;
    else if (rowi < 132) rp = 4290 + (rowi - 66);
    else { int g2 = (rowi - 132) >> 1; rp = (g2 + 1) * 66 + ((rowi - 132) & 1) * 65; }
    size_t base = ((size_t)b * 4356 + rp) * 512;
    const us4 z = {0, 0, 0, 0};
    if (t < 128) *(us4*)(xh + base + (size_t)t * 4) = z;
    else *(us4*)(xl + base + (size_t)(t - 128) * 4) = z;
  }
}

extern "C" void kernel_launch(void* const* d_in, const int* in_sizes, int n_in,
                              void* d_out, int out_size, void* d_ws, size_t ws_size,
                              hipStream_t stream) {
  (void)in_sizes; (void)n_in; (void)out_size; (void)ws_size;
  const float* x   = (const float*)d_in[0];
  const float* wk  = (const float*)d_in[1];
  const float* bk  = (const float*)d_in[2];
  const float* gam = (const float*)d_in[3];
  const float* bet = (const float*)d_in[4];
  const float* mu  = (const float*)d_in[5];
  const float* var = (const float*)d_in[6];
  const float* wv1 = (const float*)d_in[7];
  const float* bv1 = (const float*)d_in[8];
  const float* wv2 = (const float*)d_in[9];
  const float* bv2 = (const float*)d_in[10];

  const int B = 2;
  const size_t XT_E  = (size_t)B * 4356 * 512;
  const size_t WK_E  = 256 * 512;
  const size_t WV1_E = 9ull * 256 * 512;
  const size_t WV2_E = 256 * 256;
  const size_t FT_E  = (size_t)B * 4096 * 256;
  const size_t P_E   = (size_t)B * 4096 * 4096;

  size_t off = 0;
  auto carve = [&](size_t bytes) -> char* {
    off = (off + 255) & ~(size_t)255;
    char* p = (char*)d_ws + off;
    off += bytes;
    return p;
  };
  u16_t* xh  = (u16_t*)carve(XT_E * 2);
  u16_t* xl  = (u16_t*)carve(XT_E * 2);
  u16_t* wkh = (u16_t*)carve(WK_E * 2);
  u16_t* wkl = (u16_t*)carve(WK_E * 2);
  u16_t* w1h = (u16_t*)carve(WV1_E * 2);
  u16_t* w2h = (u16_t*)carve(WV2_E * 2);
  u16_t* w2l = (u16_t*)carve(WV2_E * 2);
  u16_t* fth = (u16_t*)carve(FT_E * 2);
  u16_t* ftl = (u16_t*)carve(FT_E * 2);
  u16_t* v1h = (u16_t*)carve(FT_E * 2);
  u16_t* v1l = (u16_t*)carve(FT_E * 2);
  u16_t* vh  = (u16_t*)carve(FT_E * 2);
  u16_t* Pb  = (u16_t*)carve(P_E * 2);
  float* pmax = (float*)carve(32 * 8192 * 4);
  float* psum = (float*)carve(32 * 8192 * 4);
  float* mxb  = (float*)carve(8192 * 4);
  float* rsb  = (float*)carve(8192 * 4);
  float* bnA = (float*)carve(256 * 4);
  float* bnB = (float*)carve(256 * 4);

  // Aliased scratch:
  //  big_part (Pb region): feat (2 splits) / conv (3) / wv2 (2) partials, all
  //    consumed before qk_symm<1> writes Pb. max 3x8.4MB << 67MB.
  //  pv_part (ws start): PV partials 4x8.4 = 33.6MB over xh..ftl+v1h region;
  //    all dead by PV time (fth/ftl last read by qk_symm<1>, before PV).
  float* big_part = (float*)Pb;
  float* pv_part  = (float*)d_ws;

  float* ctx = (float*)d_out;
  float* sim = (float*)d_out + (size_t)B * 256 * 4096;

  const long long FT_LL = (long long)FT_E;

  prep_all<<<5897, 256, 0, stream>>>(wk, wv2, wv1, gam, bet, mu, var, bk,
                                     wkh, wkl, w2h, w2l, w1h, bnA, bnB, xh, xl);
  xprep<<<dim3(64, 8, 2), 256, 0, stream>>>(x, xh, xl);

  // ---- feat = relu(BN(wk @ x)): MODE0, 2 K-splits of 256
  {
    GemmArgs a = {};
    a.segs[0] = {wkh,       wkl,       xh,       xl,       0};
    a.segs[1] = {wkh + 256, wkl + 256, xh + 256, xl + 256, 0};
    a.nseg = 2; a.segs_per_split = 1; a.K = 256; a.ldA = 512; a.ldB = 512;
    a.sA = 0; a.sB = (long long)4356 * 512; a.alpha = 1.f;
    a.outf = big_part; a.sOut = (long long)4096 * 256; a.sSplit = FT_LL; a.ldT = 256;
    gemm_tn<64, 128, 0, true><<<dim3(32, 4, 4), 256, 0, stream>>>(a);
    reduce_split<256, true><<<2048, 256, 0, stream>>>(big_part, FT_LL, 2, bnA, bnB, fth, ftl, FT_LL);
  }
  // ---- conv3x3 -> v1T partials: 3 ty-splits, tap-shared B staging
  {
    Conv3Args a;
    a.W = w1h; a.X = xh;
    a.outf = big_part; a.sOut = (long long)4096 * 256; a.sSplit = FT_LL;
    conv3_gemm<<<dim3(32, 2, 6), 256, 0, stream>>>(a);
    reduce_split<256, true><<<2048, 256, 0, stream>>>(big_part, FT_LL, 3, nullptr, bv1, v1h, v1l, FT_LL);
  }
  // ---- v = relu(wv2 @ v1 + bv2), flipped (M=4096, N=256), MODE0, 2 K-splits
  {
    GemmArgs a = {};
    a.segs[0] = {v1h,       v1l,       w2h,       w2l,       0};
    a.segs[1] = {v1h + 128, v1l + 128, w2h + 128, w2l + 128, 0};
    a.nseg = 2; a.segs_per_split = 1; a.K = 128; a.ldA = 256; a.ldB = 256;
    a.sA = (long long)4096 * 256; a.sB = 0; a.alpha = 1.f;
    a.outf = big_part; a.sOut = (long long)256 * 4096; a.sSplit = FT_LL; a.ldT = 4096;
    gemm_tn<128, 64, 0, false><<<dim3(4, 32, 4), 256, 0, stream>>>(a);
    reduce_split<4096, false><<<2048, 256, 0, stream>>>(big_part, FT_LL, 2, nullptr, bv2, vh, nullptr, FT_LL);
  }
  // ---- fused QK + softmax: stats pass, row-stat reduce, write pass
  {
    QkArgs a = {};
    a.fh = fth; a.fl = ftl; a.pmax = pmax; a.psum = psum;
    a.mx = mxb; a.rs = rsb; a.sim = sim; a.Pb = Pb;
    qk_symm<0><<<dim3(528, 1, 2), 256, 0, stream>>>(a);
    stat_reduce<<<32, 256, 0, stream>>>(pmax, psum, mxb, rsb);
    qk_symm<1><<<dim3(528, 1, 2), 256, 0, stream>>>(a);
  }
  // ---- ctx = P @ v^T: MODE2, NCH=8 (K_STEP 64), 4 K-splits of 1024
  {
    GemmArgs a = {};
    for (int q = 0; q < 4; ++q)
      a.segs[q] = {Pb + (size_t)q * 1024, nullptr, vh + (size_t)q * 1024, nullptr, 0};
    a.nseg = 4; a.segs_per_split = 1; a.K = 1024; a.ldA = 4096; a.ldB = 4096;
    a.sA = (long long)4096 * 4096; a.sB = (long long)256 * 4096; a.alpha = 1.f;
    a.outf = pv_part; a.sOut = (long long)256 * 4096; a.sSplit = FT_LL; a.ldT = 4096;
    gemm_tn<128, 128, 2, false, 8><<<dim3(2, 32, 8), 256, 0, stream>>>(a);
    reduce_split_f32<<<2048, 256, 0, stream>>>(pv_part, FT_LL, 4, ctx, FT_LL);
  }
}

// Round 9
// 264.541 us; speedup vs baseline: 1.1165x; 1.1165x over previous
//
#include <hip/hip_runtime.h>
#include <hip/hip_bf16.h>
#include <stdint.h>

typedef unsigned short u16_t;
typedef __attribute__((ext_vector_type(8))) short short8;
typedef __attribute__((ext_vector_type(4))) float f32x4;
typedef __attribute__((ext_vector_type(4))) unsigned short us4;

__device__ __forceinline__ float bf2f(u16_t u) {
  union { unsigned int i; float f; } c; c.i = ((unsigned int)u) << 16; return c.f;
}
__device__ __forceinline__ u16_t f2bf(float f) {
  union { float f; unsigned int i; } c; c.f = f;
  unsigned int x = c.i;
  unsigned int r = x + 0x7fffu + ((x >> 16) & 1u);
  return (u16_t)(r >> 16);
}

__device__ __forceinline__ void gload_lds16(const u16_t* g, u16_t* l) {
  __builtin_amdgcn_global_load_lds(
      (const __attribute__((address_space(1))) void*)g,
      (__attribute__((address_space(3))) void*)(unsigned int)(uintptr_t)l,
      16, 0, 0);
}

struct Seg {
  const u16_t* Ah;
  const u16_t* Al;
  const u16_t* Bh;
  const u16_t* Bl;
  int boff;
};

struct GemmArgs {
  Seg segs[9];
  int nseg;
  int segs_per_split;
  int K;
  int ldA, ldB;
  long long sA, sB;
  float alpha;
  float* outf;
  long long sOut;
  long long sSplit;
  int ldT;
};

// Fused-split TN GEMM.  MODE 0: Ah*Bh+Al*Bh+Ah*Bl; 1: Ah*Bh+Ah*Bl; 2: Ah*Bh.
// NCH = k-chunks (of 8) staged per barrier pair (4 -> K_STEP 32, 8 -> 64).
// fp32 transposed store; SYMM: upper-triangle + coalesced mirror via LDS.
template<int BM, int BN, int MODE, bool PADB, bool SYMM, int NCH = 4>
__global__ __launch_bounds__(256, 4) void gemm_tn(GemmArgs args) {
  constexpr int FM = BM / 32, FN = BN / 32;
  constexpr int AH_E = NCH * BM * 8;
  constexpr int AL_E = (MODE == 0) ? NCH * BM * 8 : 8;
  constexpr int BH_E = NCH * BN * 8;
  constexpr int BL_E = (MODE <= 1) ? NCH * BN * 8 : 8;
  constexpr int SM_E = AH_E + AL_E + BH_E + BL_E;
  static_assert(!SYMM || (size_t)SM_E * 2 >= 32 * 132 * 4, "tbuf alias too small");
  __shared__ __align__(16) u16_t smem[SM_E];
  u16_t* aflat_h = smem;
  u16_t* aflat_l = smem + AH_E;
  u16_t* bflat_h = smem + AH_E + AL_E;
  u16_t* bflat_l = smem + AH_E + AL_E + BH_E;

  const int tid = threadIdx.x;
  const int wave = tid >> 6, lane = tid & 63;
  const int lhi = lane >> 4, llo = lane & 15;
  const int wr = wave >> 1, wc = wave & 1;
  int nt, mt, b, split;
  if (SYMM) {
    b = blockIdx.z; split = 0;
    int t = blockIdx.x, r = 0;
    while (t >= 32 - r) { t -= 32 - r; ++r; }
    mt = r; nt = r + t;
  } else {
    nt = blockIdx.x; mt = blockIdx.y;
    b = blockIdx.z & 1; split = blockIdx.z >> 1;
  }
  const int row0 = mt * BM, col0 = nt * BN;

  f32x4 acc[FM][FN];
  const f32x4 zero4 = {0.f, 0.f, 0.f, 0.f};
#pragma unroll
  for (int i = 0; i < FM; ++i)
#pragma unroll
    for (int j = 0; j < FN; ++j) acc[i][j] = zero4;

  constexpr int RA = BM * NCH / 256;
  constexpr int RB = BN * NCH / 256;

  const int s0 = split * args.segs_per_split;
  int s1 = s0 + args.segs_per_split;
  if (s1 > args.nseg) s1 = args.nseg;

  for (int s = s0; s < s1; ++s) {
    const u16_t* Abh = args.segs[s].Ah + (size_t)b * args.sA;
    const u16_t* Abl = args.segs[s].Al + (size_t)b * args.sA;
    const u16_t* Bbh = args.segs[s].Bh + (size_t)b * args.sB;
    const u16_t* Bbl = args.segs[s].Bl + (size_t)b * args.sB;
    const int boff = args.segs[s].boff;
    for (int k0 = 0; k0 < args.K; k0 += NCH * 8) {
      __syncthreads();
#pragma unroll
      for (int r = 0; r < RA; ++r) {
        int idx = r * 256 + tid;
        int chunk = idx / BM, m = idx % BM;
        size_t goff = (size_t)(row0 + m) * args.ldA + (k0 + chunk * 8);
        gload_lds16(Abh + goff, aflat_h + (size_t)idx * 8);
        if (MODE == 0)
          gload_lds16(Abl + goff, aflat_l + (size_t)idx * 8);
      }
#pragma unroll
      for (int r = 0; r < RB; ++r) {
        int idx = r * 256 + tid;
        int chunk = idx / BN, n = idx % BN;
        long long rowi;
        if (PADB) {
          int gn = col0 + n;
          rowi = (long long)((gn >> 6) + 1) * 66 + (gn & 63) + 1 + boff;
        } else {
          rowi = col0 + n;
        }
        size_t goff = (size_t)rowi * args.ldB + (k0 + chunk * 8);
        gload_lds16(Bbh + goff, bflat_h + (size_t)idx * 8);
        if (MODE <= 1)
          gload_lds16(Bbl + goff, bflat_l + (size_t)idx * 8);
      }
      __syncthreads();
#pragma unroll
      for (int kk = 0; kk < NCH / 4; ++kk) {
        const int ckA = (kk * 4 + lhi) * BM;
        const int ckB = (kk * 4 + lhi) * BN;
        short8 afh[FM], afl[FM], bfh[FN], bfl[FN];
#pragma unroll
        for (int i = 0; i < FM; ++i) {
          afh[i] = *(const short8*)(aflat_h + ((size_t)ckA + wr * (BM / 2) + i * 16 + llo) * 8);
          if (MODE == 0)
            afl[i] = *(const short8*)(aflat_l + ((size_t)ckA + wr * (BM / 2) + i * 16 + llo) * 8);
        }
#pragma unroll
        for (int j = 0; j < FN; ++j) {
          bfh[j] = *(const short8*)(bflat_h + ((size_t)ckB + wc * (BN / 2) + j * 16 + llo) * 8);
          if (MODE <= 1)
            bfl[j] = *(const short8*)(bflat_l + ((size_t)ckB + wc * (BN / 2) + j * 16 + llo) * 8);
        }
#pragma unroll
        for (int i = 0; i < FM; ++i)
#pragma unroll
          for (int j = 0; j < FN; ++j) {
            f32x4 t = acc[i][j];
            if (MODE <= 1)
              t = __builtin_amdgcn_mfma_f32_16x16x32_bf16(afh[i], bfl[j], t, 0, 0, 0);
            if (MODE == 0)
              t = __builtin_amdgcn_mfma_f32_16x16x32_bf16(afl[i], bfh[j], t, 0, 0, 0);
            t = __builtin_amdgcn_mfma_f32_16x16x32_bf16(afh[i], bfh[j], t, 0, 0, 0);
            acc[i][j] = t;
          }
      }
    }
  }

  float* outp = args.outf + (size_t)split * args.sSplit + (size_t)b * args.sOut;
#pragma unroll
  for (int i = 0; i < FM; ++i) {
    int mb = row0 + wr * (BM / 2) + i * 16 + lhi * 4;
#pragma unroll
    for (int j = 0; j < FN; ++j) {
      int n = col0 + wc * (BN / 2) + j * 16 + llo;
      f32x4 vv = acc[i][j] * args.alpha;
      *(f32x4*)(outp + (size_t)n * args.ldT + mb) = vv;
    }
  }
  if (SYMM) {
    if (nt != mt) {
      float* tb = (float*)smem;  // 32x132 f32, aliases staging smem post-K-loop
#pragma unroll
      for (int i = 0; i < FM; ++i) {
        __syncthreads();
#pragma unroll
        for (int j = 0; j < FN; ++j) {
#pragma unroll
          for (int r2 = 0; r2 < 4; ++r2) {
            int trow = wr * 16 + lhi * 4 + r2;
            int tcol = wc * 64 + j * 16 + llo;
            tb[trow * 132 + tcol] = acc[i][j][r2] * args.alpha;
          }
        }
        __syncthreads();
#pragma unroll
        for (int it = 0; it < 4; ++it) {
          int idx = it * 256 + tid;
          int row = idx >> 5, c4 = idx & 31;
          int mg = row0 + (row >> 4) * 64 + i * 16 + (row & 15);
          f32x4 v4 = *(f32x4*)&tb[row * 132 + c4 * 4];
          *(f32x4*)(outp + (size_t)mg * args.ldT + col0 + c4 * 4) = v4;
        }
      }
    }
  }
}

// Conv3x3 as 3 ty-splits; the 3 tx taps share ONE staged B tile with halo.
struct Conv3Args {
  const u16_t* W;
  const u16_t* X;
  float* outf;
  long long sOut;
  long long sSplit;
};
__global__ __launch_bounds__(256, 4) void conv3_gemm(Conv3Args a) {
  __shared__ __align__(16) u16_t lA[3][4][128][8];
  __shared__ __align__(16) u16_t lB[4 * 144 * 8];
  const int tid = threadIdx.x;
  const int wave = tid >> 6, lane = tid & 63;
  const int lhi = lane >> 4, llo = lane & 15;
  const int wr = wave >> 1, wc = wave & 1;
  const int nt = blockIdx.x, mt = blockIdx.y;
  const int b = blockIdx.z & 1, ty = blockIdx.z >> 1;
  const int row0 = mt * 128;
  const int base = (2 * nt + ty) * 66;
  const u16_t* Xb = a.X + (size_t)b * 4356 * 512;
  const u16_t* Wt = a.W + (size_t)(ty * 3) * 131072;

  f32x4 acc[4][4];
  const f32x4 zero4 = {0.f, 0.f, 0.f, 0.f};
#pragma unroll
  for (int i = 0; i < 4; ++i)
#pragma unroll
    for (int j = 0; j < 4; ++j) acc[i][j] = zero4;

  for (int k0 = 0; k0 < 512; k0 += 32) {
    __syncthreads();
#pragma unroll
    for (int t = 0; t < 3; ++t)
#pragma unroll
      for (int r = 0; r < 2; ++r) {
        int slot = r * 256 + tid;
        int chunk = slot >> 7, m = slot & 127;
        const u16_t* src = Wt + (size_t)t * 131072 + (size_t)(row0 + m) * 512 + k0 + chunk * 8;
        gload_lds16(src, &lA[t][0][0][0] + (size_t)slot * 8);
      }
#pragma unroll
    for (int r = 0; r < 2; ++r) {
      int idx = r * 256 + tid;
      int chunk = idx / 144, rr = idx % 144;
      gload_lds16(Xb + (size_t)(base + rr) * 512 + k0 + chunk * 8, lB + (size_t)idx * 8);
    }
    if (tid < 64) {
      int idx = 512 + tid;
      int chunk = idx / 144, rr = idx % 144;
      gload_lds16(Xb + (size_t)(base + rr) * 512 + k0 + chunk * 8, lB + (size_t)idx * 8);
    }
    __syncthreads();
#pragma unroll
    for (int t = 0; t < 3; ++t) {
      short8 af[4], bf[4];
#pragma unroll
      for (int i = 0; i < 4; ++i)
        af[i] = *(const short8*)&lA[t][lhi][wr * 64 + i * 16 + llo][0];
#pragma unroll
      for (int j = 0; j < 4; ++j) {
        int rB = wc * 66 + j * 16 + llo + t;
        bf[j] = *(const short8*)(lB + ((size_t)lhi * 144 + rB) * 8);
      }
#pragma unroll
      for (int i = 0; i < 4; ++i)
#pragma unroll
        for (int j = 0; j < 4; ++j)
          acc[i][j] = __builtin_amdgcn_mfma_f32_16x16x32_bf16(af[i], bf[j], acc[i][j], 0, 0, 0);
    }
  }

  float* outp = a.outf + (size_t)ty * a.sSplit + (size_t)b * a.sOut;
#pragma unroll
  for (int i = 0; i < 4; ++i) {
    int mb = row0 + wr * 64 + i * 16 + lhi * 4;
#pragma unroll
    for (int j = 0; j < 4; ++j) {
      int n = (nt << 7) + wc * 64 + j * 16 + llo;
      *(f32x4*)(outp + (size_t)n * 256 + mb) = acc[i][j];
    }
  }
}

template<int LDT, bool PER_COL>
__global__ __launch_bounds__(256) void reduce_split(
    const float* __restrict__ part, long long sSplit, int ns,
    const float* __restrict__ scale, const float* __restrict__ bias,
    u16_t* __restrict__ oh, u16_t* __restrict__ ol, long long total) {
  long long i = ((long long)blockIdx.x * 256 + threadIdx.x) * 4;
  if (i >= total) return;
  f32x4 s = *(const f32x4*)(part + i);
  for (int p = 1; p < ns; ++p) s += *(const f32x4*)(part + (size_t)p * sSplit + i);
  f32x4 v;
  if (PER_COL) {
    int c = (int)(i & (LDT - 1));
    f32x4 bi = *(const f32x4*)(bias + c);
    if (scale) { f32x4 sc = *(const f32x4*)(scale + c); v = s * sc + bi; }
    else v = s + bi;
  } else {
    int r = (int)((i / LDT) & 255);
    float bi = bias[r];
    v = s + bi;
  }
  us4 h, l;
#pragma unroll
  for (int c2 = 0; c2 < 4; ++c2) {
    float vv = v[c2] > 0.f ? v[c2] : 0.f;
    u16_t hh = f2bf(vv);
    h[c2] = hh;
    l[c2] = f2bf(vv - bf2f(hh));
  }
  *(us4*)(oh + i) = h;
  if (ol) *(us4*)(ol + i) = l;
}

__global__ __launch_bounds__(256) void reduce_split_f32(
    const float* __restrict__ part, long long sSplit, int ns,
    float* __restrict__ out, long long total) {
  long long i = ((long long)blockIdx.x * 256 + threadIdx.x) * 4;
  if (i >= total) return;
  f32x4 s = *(const f32x4*)(part + i);
  for (int p = 1; p < ns; ++p) s += *(const f32x4*)(part + (size_t)p * sSplit + i);
  __builtin_nontemporal_store(s, (f32x4*)(out + i));  // ctx: write-once, never re-read
}

// Row softmax over 4096, in-place fp32 + bf16 copy for PV.
__global__ __launch_bounds__(256) void softmax_k(float* S, u16_t* P) {
  const int row = blockIdx.x;
  float* Sr = S + (size_t)row * 4096;
  u16_t* Pr = P + (size_t)row * 4096;
  const int t = threadIdx.x;
  const int wave = t >> 6;
  f32x4 v[4];
  float vmax = -3.4e38f;
#pragma unroll
  for (int i = 0; i < 4; ++i) {
    v[i] = ((const f32x4*)Sr)[t + i * 256];
#pragma unroll
    for (int c = 0; c < 4; ++c) vmax = fmaxf(vmax, v[i][c]);
  }
#pragma unroll
  for (int off = 32; off; off >>= 1) vmax = fmaxf(vmax, __shfl_xor(vmax, off));
  __shared__ float red[4];
  if ((t & 63) == 0) red[wave] = vmax;
  __syncthreads();
  vmax = fmaxf(fmaxf(red[0], red[1]), fmaxf(red[2], red[3]));
  float sum = 0.f;
#pragma unroll
  for (int i = 0; i < 4; ++i)
#pragma unroll
    for (int c = 0; c < 4; ++c) { v[i][c] = __expf(v[i][c] - vmax); sum += v[i][c]; }
#pragma unroll
  for (int off = 32; off; off >>= 1) sum += __shfl_xor(sum, off);
  __shared__ float red2[4];
  if ((t & 63) == 0) red2[wave] = sum;
  __syncthreads();
  sum = red2[0] + red2[1] + red2[2] + red2[3];
  float rs = 1.0f / sum;
#pragma unroll
  for (int i = 0; i < 4; ++i) {
    f32x4 o = v[i] * rs;
    __builtin_nontemporal_store(o, (f32x4*)Sr + t + i * 256);  // sim: write-once
    us4 pb;
#pragma unroll
    for (int c = 0; c < 4; ++c) pb[c] = f2bf(o[c]);
    ((us4*)Pr)[t + i * 256] = pb;  // Pb re-read by PV: keep cached
  }
}

// x [2][512][4096] -> padded transposed split xT [2][4356][512] (hi/lo bf16).
__global__ __launch_bounds__(256) void xprep(const float* __restrict__ x,
                                             u16_t* __restrict__ xh, u16_t* __restrict__ xl) {
  __shared__ float tile[64][65];
  const int b = blockIdx.z, c0 = blockIdx.y * 64, n0 = blockIdx.x * 64;
  const float* xb = x + ((size_t)b * 512 + c0) * 4096 + n0;
  const int t = threadIdx.x;
  const int tr = t >> 6, tc = t & 63;
#pragma unroll
  for (int rr = 0; rr < 16; ++rr) {
    int ci = tr + rr * 4;
    tile[ci][tc] = xb[(size_t)ci * 4096 + tc];
  }
  __syncthreads();
#pragma unroll
  for (int rr = 0; rr < 16; ++rr) {
    int nj = rr * 4 + tr;
    float v = tile[tc][nj];
    size_t rp = (size_t)(blockIdx.x + 1) * 66 + nj + 1;
    size_t o = ((size_t)b * 4356 + rp) * 512 + c0 + tc;
    u16_t hh = f2bf(v);
    xh[o] = hh;
    xl[o] = f2bf(v - bf2f(hh));
  }
}

// Fused prep: bn | wk split | wv2 split | wv1 remap | zeropad
__global__ __launch_bounds__(256) void prep_all(
    const float* __restrict__ wk, const float* __restrict__ wv2, const float* __restrict__ wv1,
    const float* __restrict__ g, const float* __restrict__ be, const float* __restrict__ mu,
    const float* __restrict__ var, const float* __restrict__ bkb,
    u16_t* __restrict__ wkh, u16_t* __restrict__ wkl,
    u16_t* __restrict__ w2h, u16_t* __restrict__ w2l,
    u16_t* __restrict__ w1h, float* __restrict__ bnA, float* __restrict__ bnB,
    u16_t* __restrict__ xh, u16_t* __restrict__ xl) {
  long long i = (long long)blockIdx.x * 256 + threadIdx.x;
  if (i < 256) {
    float s = g[i] * rsqrtf(var[i] + 1e-5f);
    bnA[i] = s;
    bnB[i] = (bkb[i] - mu[i]) * s + be[i];
    return;
  }
  i -= 256;
  if (i < 131072) {
    float v = wk[i];
    u16_t hh = f2bf(v);
    wkh[i] = hh; wkl[i] = f2bf(v - bf2f(hh));
    return;
  }
  i -= 131072;
  if (i < 65536) {
    float v = wv2[i];
    u16_t hh = f2bf(v);
    w2h[i] = hh; w2l[i] = f2bf(v - bf2f(hh));
    return;
  }
  i -= 65536;
  if (i < 1179648) {
    int tp = (int)(i / (256 * 512));
    int rem = (int)(i % (256 * 512));
    int o = rem / 512, c = rem % 512;
    w1h[i] = f2bf(wv1[((size_t)o * 512 + c) * 9 + tp]);
    return;
  }
  i -= 1179648;
  if (i < 133120) {
    int blk = (int)(i >> 8), t = (int)(i & 255);
    int rowi = blk % 260, b = blk / 260;
    int rp;
    if (rowi < 66) rp = rowi;
    else if (rowi < 132) rp = 4290 + (rowi - 66);
    else { int g2 = (rowi - 132) >> 1; rp = (g2 + 1) * 66 + ((rowi - 132) & 1) * 65; }
    size_t base = ((size_t)b * 4356 + rp) * 512;
    const us4 z = {0, 0, 0, 0};
    if (t < 128) *(us4*)(xh + base + (size_t)t * 4) = z;
    else *(us4*)(xl + base + (size_t)(t - 128) * 4) = z;
  }
}

extern "C" void kernel_launch(void* const* d_in, const int* in_sizes, int n_in,
                              void* d_out, int out_size, void* d_ws, size_t ws_size,
                              hipStream_t stream) {
  (void)in_sizes; (void)n_in; (void)out_size; (void)ws_size;
  const float* x   = (const float*)d_in[0];
  const float* wk  = (const float*)d_in[1];
  const float* bk  = (const float*)d_in[2];
  const float* gam = (const float*)d_in[3];
  const float* bet = (const float*)d_in[4];
  const float* mu  = (const float*)d_in[5];
  const float* var = (const float*)d_in[6];
  const float* wv1 = (const float*)d_in[7];
  const float* bv1 = (const float*)d_in[8];
  const float* wv2 = (const float*)d_in[9];
  const float* bv2 = (const float*)d_in[10];

  const int B = 2;
  const size_t XT_E  = (size_t)B * 4356 * 512;
  const size_t WK_E  = 256 * 512;
  const size_t WV1_E = 9ull * 256 * 512;
  const size_t WV2_E = 256 * 256;
  const size_t FT_E  = (size_t)B * 4096 * 256;
  const size_t P_E   = (size_t)B * 4096 * 4096;

  size_t off = 0;
  auto carve = [&](size_t bytes) -> char* {
    off = (off + 255) & ~(size_t)255;
    char* p = (char*)d_ws + off;
    off += bytes;
    return p;
  };
  u16_t* xh  = (u16_t*)carve(XT_E * 2);
  u16_t* xl  = (u16_t*)carve(XT_E * 2);
  u16_t* wkh = (u16_t*)carve(WK_E * 2);
  u16_t* wkl = (u16_t*)carve(WK_E * 2);
  u16_t* w1h = (u16_t*)carve(WV1_E * 2);
  u16_t* w2h = (u16_t*)carve(WV2_E * 2);
  u16_t* w2l = (u16_t*)carve(WV2_E * 2);
  u16_t* fth = (u16_t*)carve(FT_E * 2);
  u16_t* ftl = (u16_t*)carve(FT_E * 2);
  u16_t* v1h = (u16_t*)carve(FT_E * 2);
  u16_t* v1l = (u16_t*)carve(FT_E * 2);
  u16_t* vh  = (u16_t*)carve(FT_E * 2);
  u16_t* Pb  = (u16_t*)carve(P_E * 2);
  float* bnA = (float*)carve(256 * 4);
  float* bnB = (float*)carve(256 * 4);

  // Aliased scratch: big_part (Pb region) for feat/conv/wv2 partials (max
  // 3x8.4MB << 134MB), all dead before softmax writes Pb. pv_part (ws start)
  // 33.5MB over xh..fth region, all dead by PV time, rewritten per call.
  float* big_part = (float*)Pb;
  float* pv_part  = (float*)d_ws;

  float* ctx = (float*)d_out;
  float* sim = (float*)d_out + (size_t)B * 256 * 4096;

  const long long FT_LL = (long long)FT_E;

  prep_all<<<5897, 256, 0, stream>>>(wk, wv2, wv1, gam, bet, mu, var, bk,
                                     wkh, wkl, w2h, w2l, w1h, bnA, bnB, xh, xl);
  xprep<<<dim3(64, 8, 2), 256, 0, stream>>>(x, xh, xl);

  // ---- feat = relu(BN(wk @ x)): MODE0, 2 K-splits of 256
  {
    GemmArgs a = {};
    a.segs[0] = {wkh,       wkl,       xh,       xl,       0};
    a.segs[1] = {wkh + 256, wkl + 256, xh + 256, xl + 256, 0};
    a.nseg = 2; a.segs_per_split = 1; a.K = 256; a.ldA = 512; a.ldB = 512;
    a.sA = 0; a.sB = (long long)4356 * 512; a.alpha = 1.f;
    a.outf = big_part; a.sOut = (long long)4096 * 256; a.sSplit = FT_LL; a.ldT = 256;
    gemm_tn<64, 128, 0, true, false><<<dim3(32, 4, 4), 256, 0, stream>>>(a);
    reduce_split<256, true><<<2048, 256, 0, stream>>>(big_part, FT_LL, 2, bnA, bnB, fth, ftl, FT_LL);
  }
  // ---- QK: S = fth @ (fth+ftl)^T * Ck^-0.5, MODE1, symmetric upper-triangle
  {
    GemmArgs a = {};
    a.segs[0] = {fth, nullptr, fth, ftl, 0};
    a.nseg = 1; a.segs_per_split = 1; a.K = 256; a.ldA = 256; a.ldB = 256;
    a.sA = (long long)4096 * 256; a.sB = (long long)4096 * 256; a.alpha = 0.0625f;
    a.outf = sim; a.sOut = (long long)4096 * 4096; a.sSplit = 0; a.ldT = 4096;
    gemm_tn<128, 128, 1, false, true><<<dim3(528, 1, 2), 256, 0, stream>>>(a);
  }
  // ---- conv3x3 -> v1T partials: 3 ty-splits, tap-shared B staging
  {
    Conv3Args a;
    a.W = w1h; a.X = xh;
    a.outf = big_part; a.sOut = (long long)4096 * 256; a.sSplit = FT_LL;
    conv3_gemm<<<dim3(32, 2, 6), 256, 0, stream>>>(a);
    reduce_split<256, true><<<2048, 256, 0, stream>>>(big_part, FT_LL, 3, nullptr, bv1, v1h, v1l, FT_LL);
  }
  // ---- v = relu(wv2 @ v1 + bv2), flipped (M=4096, N=256), MODE0, 2 K-splits
  {
    GemmArgs a = {};
    a.segs[0] = {v1h,       v1l,       w2h,       w2l,       0};
    a.segs[1] = {v1h + 128, v1l + 128, w2h + 128, w2l + 128, 0};
    a.nseg = 2; a.segs_per_split = 1; a.K = 128; a.ldA = 256; a.ldB = 256;
    a.sA = (long long)4096 * 256; a.sB = 0; a.alpha = 1.f;
    a.outf = big_part; a.sOut = (long long)256 * 4096; a.sSplit = FT_LL; a.ldT = 4096;
    gemm_tn<128, 64, 0, false, false><<<dim3(4, 32, 4), 256, 0, stream>>>(a);
    reduce_split<4096, false><<<2048, 256, 0, stream>>>(big_part, FT_LL, 2, nullptr, bv2, vh, nullptr, FT_LL);
  }
  softmax_k<<<B * 4096, 256, 0, stream>>>(sim, Pb);
  // ---- ctx = P @ v^T: MODE2, NCH=8 (K_STEP 64), 4 K-splits of 1024
  {
    GemmArgs a = {};
    for (int q = 0; q < 4; ++q)
      a.segs[q] = {Pb + (size_t)q * 1024, nullptr, vh + (size_t)q * 1024, nullptr, 0};
    a.nseg = 4; a.segs_per_split = 1; a.K = 1024; a.ldA = 4096; a.ldB = 4096;
    a.sA = (long long)4096 * 4096; a.sB = (long long)256 * 4096; a.alpha = 1.f;
    a.outf = pv_part; a.sOut = (long long)256 * 4096; a.sSplit = FT_LL; a.ldT = 4096;
    gemm_tn<128, 128, 2, false, false, 8><<<dim3(2, 32, 8), 256, 0, stream>>>(a);
    reduce_split_f32<<<2048, 256, 0, stream>>>(pv_part, FT_LL, 4, ctx, FT_LL);
  }
}